// Round 2
// baseline (541.446 us; speedup 1.0000x reference)
//
#include <hip/hip_runtime.h>

#define F      128
#define NPAIR  8128   // F*(F-1)/2
#define OUTW   8256   // F + NPAIR
#define NQUAD  (NPAIR / 4)  // 2032 float4 per row

typedef float f4 __attribute__((ext_vector_type(4)));

__global__ __launch_bounds__(256) void feat_inter_kernel(
    const float* __restrict__ x, float* __restrict__ out)
{
    __shared__ float xs[F];

    const int row = blockIdx.x;
    const int tid = threadIdx.x;
    const float* xr   = x   + (size_t)row * F;
    float*       orow = out + (size_t)row * OUTW;

    // Stage row into LDS
    if (tid < F) xs[tid] = xr[tid];
    __syncthreads();

    // Copy x itself to output head: 128 floats = 32 float4 stores
    if (tid < 32) {
        f4 v;
        v.x = xs[tid * 4 + 0];
        v.y = xs[tid * 4 + 1];
        v.z = xs[tid * 4 + 2];
        v.w = xs[tid * 4 + 3];
        __builtin_nontemporal_store(v, (f4*)orow + tid);
    }

    // Interactions: k in [0, 8128), pair (i,j), i<j, row-major triu order.
    // off(i) = i*127 - i*(i-1)/2 ; i = floor((255 - sqrt(65025 - 8k)) / 2)
    f4* odst = (f4*)(orow + F);
    for (int q = tid; q < NQUAD; q += 256) {
        const int k0 = q * 4;
        f4 v;
#pragma unroll
        for (int u = 0; u < 4; ++u) {
            const int k = k0 + u;
            const float disc = 65025.0f - 8.0f * (float)k;
            int i = (int)((255.0f - sqrtf(disc)) * 0.5f);
            int offi = i * 127 - ((i * (i - 1)) >> 1);
            // safety correction (should never trigger; exactness argued in R0)
            if (k < offi) {
                --i;
                offi = i * 127 - ((i * (i - 1)) >> 1);
            } else {
                const int offn = offi + (127 - i);
                if (k >= offn) { ++i; offi = offn; }
            }
            const int j = i + 1 + (k - offi);
            v[u] = xs[i] * xs[j];
        }
        __builtin_nontemporal_store(v, odst + q);
    }
}

extern "C" void kernel_launch(void* const* d_in, const int* in_sizes, int n_in,
                              void* d_out, int out_size, void* d_ws, size_t ws_size,
                              hipStream_t stream) {
    const float* x  = (const float*)d_in[0];
    float*      out = (float*)d_out;
    const int rows = in_sizes[0] / F;  // 16384
    feat_inter_kernel<<<rows, 256, 0, stream>>>(x, out);
}